// Round 7
// baseline (423.602 us; speedup 1.0000x reference)
//
#include <hip/hip_runtime.h>
#include <hip/hip_bf16.h>

#define N_NODES 50000
#define N_EDGES 600000
#define SLOTS 64
#define GEMM_BLOCKS 782    // 782*64 = 50048 >= 50000 rows
#define BUILD_BLOCKS 2344  // 2344*256 >= 600000 edges (1 edge/thread)
#define TOTAL_BLOCKS (GEMM_BLOCKS + BUILD_BLOCKS)   // 3126
#define GATHER_BLOCKS 3125 // 3125*16 = 50000 exactly
#define ACC_BANKS 8        // banked BN accumulators: same-address chains 3125/8

// ---- workspace layout (bytes) ----
#define Z_OFF        0ull           // bf16-packed dwords [50000*64] = 12,800,000 (Z = h@W, unscaled)
#define ESRCP_OFF    12800000ull    // ushort[50000*64] padded adjacency = 6,400,000
#define CURS_OFF     19200000ull    // int[50000] dense (zeroed; ends as deg_in)
#define DEGO_OFF     19400000ull    // int[50000] dense (zeroed)
#define ACC1_OFF     19600000ull    // float[8*128] banked BN sum (zeroed) = 4096
#define ACC2_OFF     19604096ull    // float[8*128] banked BN sumsq (zeroed) = 4096
#define DONE_OFF     19608192ull    // int[1] (zeroed)
#define ZERO_OFF     19200000ull
#define ZERO_BYTES   408256ull      // cursor+dego+acc1+acc2+done (contiguous)
#define SCALE_OFF    22801280ull    // float[128]
#define SHIFT_OFF    22801792ull    // float[128]
#define OUTPRE_OFF   23000064ull    // bf16-packed [50000*64 dwords] = 12,800,000

typedef short bf16x8 __attribute__((ext_vector_type(8)));
typedef float f32x4  __attribute__((ext_vector_type(4)));

__device__ __forceinline__ float bf16lo(unsigned int v) { return __uint_as_float(v << 16); }
__device__ __forceinline__ float bf16hi(unsigned int v) { return __uint_as_float(v & 0xffff0000u); }
__device__ __forceinline__ unsigned int packbf16(float x, float y) {
  union { __hip_bfloat162 v; unsigned int u; } cvt;
  cvt.v.x = __float2bfloat16(x);
  cvt.v.y = __float2bfloat16(y);
  return cvt.u;
}

// dtype self-detect: 64-sample per-wave ballot on h's first dwords.
__device__ __forceinline__ int detect_bf16(const unsigned int* hu, int tid) {
  unsigned int u = hu[tid & 63];
  int ex = (u >> 7) & 0xFF;
  unsigned long long b = __ballot(ex >= 100 && ex <= 140);
  return __popcll(b) >= 32 ? 1 : 0;
}

// ---------------- fused: GEMM (Z = h@W, unscaled) || CSR build + dego -------
// Champion structure (R1/R5): GEMM blocks [0,782), build blocks [782,3126).
// deg scales commute with the GEMM; applied per-src at gather.
// Build is bound by memory-side atomic service (~1.2M RMWs ~= 60us floor,
// robust across layouts per R0/R1/R2); the GEMM rides free in that shadow.
__global__ __launch_bounds__(256) void k_fused(const int* __restrict__ src,
                                               const int* __restrict__ dst,
                                               int* __restrict__ cursor,
                                               int* __restrict__ dego,
                                               unsigned short* __restrict__ esrcPad,
                                               const void* __restrict__ hraw,
                                               const void* __restrict__ Wraw,
                                               __hip_bfloat16* __restrict__ Z) {
  __shared__ unsigned int lb[8192];      // swizzled W B-frags (32 KB) -> 5 blocks/CU
  int t = threadIdx.x;

  if (blockIdx.x >= GEMM_BLOCKS) {
    // ---- build path: 2 atomics + dependent 2B scatter per edge ----
    int e = (blockIdx.x - GEMM_BLOCKS) * 256 + t;
    if (e < N_EDGES) {
      int s = src[e];
      int d = dst[e];
      atomicAdd(&dego[s], 1);
      int slot = atomicAdd(&cursor[d], 1);
      if (slot < SLOTS) esrcPad[(size_t)d * SLOTS + slot] = (unsigned short)s;
    }
    return;
  }

  // ---- GEMM path ----
  const unsigned int* hu = (const unsigned int*)hraw;
  int isbf = detect_bf16(hu, t);
  int r0 = blockIdx.x * 64;

  // inline W swizzle: global W -> LDS B-frag layout (hidden under build shadow)
  for (int i = t; i < 8192; i += 256) {
    int tileIdx = i >> 8;
    int rem     = i & 255;
    int ln      = rem >> 2;
    int dw      = rem & 3;
    int kb      = tileIdx & 3;
    int ct      = tileIdx >> 2;
    int q       = ln >> 4;
    int n       = ln & 15;
    int k       = kb * 32 + q * 8 + dw * 2;
    int c       = ct * 16 + n;
    unsigned int val;
    if (isbf) {
      const unsigned int* Wd = (const unsigned int*)Wraw;
      unsigned int u0 = Wd[k * 64 + (c >> 1)];
      unsigned int u1 = Wd[(k + 1) * 64 + (c >> 1)];
      unsigned int h0 = (c & 1) ? (u0 >> 16) : (u0 & 0xffffu);
      unsigned int h1 = (c & 1) ? (u1 >> 16) : (u1 & 0xffffu);
      val = h0 | (h1 << 16);
    } else {
      const float* Wf = (const float*)Wraw;
      val = packbf16(Wf[k * 128 + c], Wf[(k + 1) * 128 + c]);
    }
    lb[i] = val;
  }

  int l = t & 63;
  int w = t >> 6;
  int m = l & 15;
  int q = l >> 4;

  int rA = r0 + w * 16 + m;
  bool okA = rA < N_NODES;

  // A fragments straight from global h, converted inline
  bf16x8 af[4];
  if (isbf) {
    const uint4* hd = (const uint4*)hraw;
#pragma unroll
    for (int kb = 0; kb < 4; ++kb) {
      union { uint4 u; bf16x8 v; } cv;
      cv.u = okA ? hd[(size_t)rA * 16 + kb * 4 + q] : make_uint4(0u, 0u, 0u, 0u);
      af[kb] = cv.v;
    }
  } else {
    const float4* hf = (const float4*)hraw;
#pragma unroll
    for (int kb = 0; kb < 4; ++kb) {
      union { uint4 u; bf16x8 v; } cv;
      if (okA) {
        float4 f0 = hf[(size_t)rA * 32 + kb * 8 + q * 2];
        float4 f1 = hf[(size_t)rA * 32 + kb * 8 + q * 2 + 1];
        cv.u.x = packbf16(f0.x, f0.y);
        cv.u.y = packbf16(f0.z, f0.w);
        cv.u.z = packbf16(f1.x, f1.y);
        cv.u.w = packbf16(f1.z, f1.w);
      } else {
        cv.u = make_uint4(0u, 0u, 0u, 0u);
      }
      af[kb] = cv.v;
    }
  }

  f32x4 acc[8];
#pragma unroll
  for (int ct = 0; ct < 8; ++ct) acc[ct] = (f32x4){0.f, 0.f, 0.f, 0.f};

  __syncthreads();

#pragma unroll
  for (int kb = 0; kb < 4; ++kb) {
#pragma unroll
    for (int ct = 0; ct < 8; ++ct) {
      bf16x8 bfv = *(const bf16x8*)&lb[(ct * 4 + kb) * 256 + l * 4];
      acc[ct] = __builtin_amdgcn_mfma_f32_16x16x32_bf16(af[kb], bfv, acc[ct], 0, 0, 0);
    }
  }

#pragma unroll
  for (int ct = 0; ct < 8; ++ct) {
    int col = ct * 16 + m;
#pragma unroll
    for (int reg = 0; reg < 4; ++reg) {
      int row = r0 + w * 16 + q * 4 + reg;
      if (row < N_NODES) Z[(size_t)row * 128 + col] = __float2bfloat16(acc[ct][reg]);
    }
  }
}

// ---------------- gather + BN partials + banked-acc + last-block finalize ---
// Gather unchanged from R5. BN partials go straight into 8 banked global
// accumulators via atomicAdd (memory-side, XCD-coherent); the 3125th block
// to finish (threadfence last-block pattern, validated in R5's k_bnredfin)
// sums the banks and writes scale/shift. Removes the k_bnredfin dispatch and
// the psum/psq round-trip. No block ever waits -> no spin pathology.
__global__ __launch_bounds__(256) void k_gatherBN(const unsigned int* __restrict__ Zd,
                                                  const int* __restrict__ cursor,
                                                  const int* __restrict__ dego,
                                                  const unsigned short* __restrict__ esrcPad,
                                                  unsigned int* __restrict__ outpre,
                                                  float* __restrict__ acc1,
                                                  float* __restrict__ acc2,
                                                  int* __restrict__ done,
                                                  const void* __restrict__ gamma,
                                                  const void* __restrict__ beta,
                                                  const unsigned int* __restrict__ hu,
                                                  float* __restrict__ scale,
                                                  float* __restrict__ shift) {
  __shared__ float sred[8 * 128];   // [0,512): sum partials, [512,1024): sq partials
  __shared__ int lastflag;
  int t = threadIdx.x;
  int w = t >> 6;
  int l = t & 63;
  if (t == 0) lastflag = 0;
  float s1a = 0.f, s1b = 0.f, s2a = 0.f, s2b = 0.f;
#pragma unroll
  for (int i = 0; i < 4; ++i) {
    int n = blockIdx.x * 16 + w * 4 + i;       // covers 0..49999 exactly
    int di = cursor[n];
    int cnt = di < SLOTS ? di : SLOTS;
    const unsigned short* row = esrcPad + (size_t)n * SLOTS;
    float a0 = 0.f, a1 = 0.f;
    int j = 0;
    for (; j + 3 < cnt; j += 4) {
      ushort4 s4 = *(const ushort4*)&row[j];
      int i0 = s4.x, i1 = s4.y, i2 = s4.z, i3 = s4.w;
      unsigned int v0 = Zd[(size_t)i0 * 64 + l];
      unsigned int v1 = Zd[(size_t)i1 * 64 + l];
      unsigned int v2 = Zd[(size_t)i2 * 64 + l];
      unsigned int v3 = Zd[(size_t)i3 * 64 + l];
      float c0 = rsqrtf((float)max(dego[i0], 1));
      float c1 = rsqrtf((float)max(dego[i1], 1));
      float c2 = rsqrtf((float)max(dego[i2], 1));
      float c3 = rsqrtf((float)max(dego[i3], 1));
      a0 = fmaf(bf16lo(v0), c0, a0); a1 = fmaf(bf16hi(v0), c0, a1);
      a0 = fmaf(bf16lo(v1), c1, a0); a1 = fmaf(bf16hi(v1), c1, a1);
      a0 = fmaf(bf16lo(v2), c2, a0); a1 = fmaf(bf16hi(v2), c2, a1);
      a0 = fmaf(bf16lo(v3), c3, a0); a1 = fmaf(bf16hi(v3), c3, a1);
    }
    for (; j < cnt; ++j) {
      int is = row[j];
      unsigned int v = Zd[(size_t)is * 64 + l];
      float c = rsqrtf((float)max(dego[is], 1));
      a0 = fmaf(bf16lo(v), c, a0);
      a1 = fmaf(bf16hi(v), c, a1);
    }
    float scn = rsqrtf((float)(di < 1 ? 1 : di));
    a0 *= scn; a1 *= scn;
    outpre[(size_t)n * 64 + l] = packbf16(a0, a1);
    s1a += a0; s2a += a0 * a0;
    s1b += a1; s2b += a1 * a1;
  }
  sred[w * 128 + 2 * l]           = s1a;
  sred[w * 128 + 2 * l + 1]       = s1b;
  sred[512 + w * 128 + 2 * l]     = s2a;
  sred[512 + w * 128 + 2 * l + 1] = s2b;
  __syncthreads();
  int bank = (blockIdx.x & (ACC_BANKS - 1)) * 128;
  if (t < 128) {
    atomicAdd(&acc1[bank + t], sred[t] + sred[128 + t] + sred[256 + t] + sred[384 + t]);
    atomicAdd(&acc2[bank + t], sred[512 + t] + sred[640 + t] + sred[768 + t] + sred[896 + t]);
  }
  __threadfence();           // order our acc atomics before the done bump
  __syncthreads();
  if (t == 0) {
    if (atomicAdd(done, 1) == GATHER_BLOCKS - 1) lastflag = 1;
  }
  __syncthreads();
  if (lastflag) {
    int isbf = detect_bf16(hu, t);
    if (t < 128) {
      float S1 = 0.f, S2 = 0.f;
#pragma unroll
      for (int k = 0; k < ACC_BANKS; ++k) {
        S1 += atomicAdd(&acc1[k * 128 + t], 0.f);   // memory-side coherent reads
        S2 += atomicAdd(&acc2[k * 128 + t], 0.f);
      }
      const float invN = 1.0f / (float)N_NODES;
      float mu  = S1 * invN;
      float var = S2 * invN - mu * mu;
      float is  = rsqrtf(var + 1e-5f);
      float g, b;
      if (isbf) {
        g = __bfloat162float(((const __hip_bfloat16*)gamma)[t]);
        b = __bfloat162float(((const __hip_bfloat16*)beta)[t]);
      } else {
        g = ((const float*)gamma)[t];
        b = ((const float*)beta)[t];
      }
      scale[t] = g * is;                 // visible to k_rownorm via kernel boundary
      shift[t] = b - mu * g * is;
    }
  }
}

// ---------------- BN apply + ReLU + row L2 normalize + store ----------------
__global__ __launch_bounds__(256) void k_rownorm(const unsigned int* __restrict__ outpre,
                                                 const float* __restrict__ scale,
                                                 const float* __restrict__ shift,
                                                 const unsigned int* __restrict__ hu,
                                                 void* __restrict__ outraw) {
  int t = threadIdx.x;
  int isbf = detect_bf16(hu, t);
  int r = blockIdx.x * 4 + (t >> 6);   // grid = N_NODES/4 exactly
  int l = t & 63;
  unsigned int xv = outpre[(size_t)r * 64 + l];
  float2 sc = *(const float2*)&scale[2 * l];
  float2 sh = *(const float2*)&shift[2 * l];
  float y0 = fmaxf(bf16lo(xv) * sc.x + sh.x, 0.f);
  float y1 = fmaxf(bf16hi(xv) * sc.y + sh.y, 0.f);
  float ss = y0 * y0 + y1 * y1;
#pragma unroll
  for (int o = 1; o < 64; o <<= 1) ss += __shfl_xor(ss, o, 64);
  float inv = 1.0f / fmaxf(sqrtf(ss), 1e-12f);
  y0 *= inv; y1 *= inv;
  if (isbf) {
    ((unsigned int*)outraw)[(size_t)r * 64 + l] = packbf16(y0, y1);
  } else {
    float2 o2; o2.x = y0; o2.y = y1;
    ((float2*)outraw)[(size_t)r * 64 + l] = o2;
  }
}

extern "C" void kernel_launch(void* const* d_in, const int* in_sizes, int n_in,
                              void* d_out, int out_size, void* d_ws, size_t ws_size,
                              hipStream_t stream) {
  const void* h     = d_in[0];
  const void* W     = d_in[1];
  const void* gamma = d_in[2];
  const void* beta  = d_in[3];
  const int*  src   = (const int*)d_in[4];
  const int*  dst   = (const int*)d_in[5];

  char* ws = (char*)d_ws;
  unsigned int* Zd        = (unsigned int*)(ws + Z_OFF);
  unsigned short* esrcPad = (unsigned short*)(ws + ESRCP_OFF);
  int*   cursor  = (int*)(ws + CURS_OFF);
  int*   dego    = (int*)(ws + DEGO_OFF);
  float* acc1    = (float*)(ws + ACC1_OFF);
  float* acc2    = (float*)(ws + ACC2_OFF);
  int*   done    = (int*)(ws + DONE_OFF);
  float* scale   = (float*)(ws + SCALE_OFF);
  float* shift   = (float*)(ws + SHIFT_OFF);
  unsigned int* outpre = (unsigned int*)(ws + OUTPRE_OFF);   // bf16-packed

  (void)hipMemsetAsync(ws + ZERO_OFF, 0, ZERO_BYTES, stream);

  hipLaunchKernelGGL(k_fused, dim3(TOTAL_BLOCKS), dim3(256), 0, stream,
                     src, dst, cursor, dego, esrcPad, h, W, (__hip_bfloat16*)Zd);
  hipLaunchKernelGGL(k_gatherBN, dim3(GATHER_BLOCKS), dim3(256), 0, stream,
                     Zd, cursor, dego, esrcPad, outpre,
                     acc1, acc2, done, gamma, beta,
                     (const unsigned int*)h, scale, shift);
  hipLaunchKernelGGL(k_rownorm, dim3(N_NODES / 4), dim3(256), 0, stream,
                     outpre, scale, shift, (const unsigned int*)h, (unsigned int*)d_out);
}

// Round 8
// 186.306 us; speedup vs baseline: 2.2737x; 2.2737x over previous
//
#include <hip/hip_runtime.h>
#include <hip/hip_bf16.h>

#define N_NODES 50000
#define N_EDGES 600000
#define SLOTS 64
#define GEMM_BLOCKS 782    // 782*64 = 50048 >= 50000 rows
#define BUILD_BLOCKS 2344  // 2344*256 >= 600000 edges (1 edge/thread)
#define TOTAL_BLOCKS (GEMM_BLOCKS + BUILD_BLOCKS)   // 3126
#define GATHER_BLOCKS 3125 // 3125*16 = 50000 exactly
#define ACC_BANKS 8        // banked BN accumulators: same-address chains 3125/8

// ---- workspace layout (bytes) ----
#define Z_OFF        0ull           // bf16-packed dwords [50000*64] = 12,800,000 (Z = h@W, unscaled)
#define ESRCP_OFF    12800000ull    // ushort[50000*64] padded adjacency = 6,400,000
#define CURS_OFF     19200000ull    // int[50000] dense (zeroed; ends as deg_in)
#define DEGO_OFF     19400000ull    // int[50000] dense (zeroed)
#define ACC1_OFF     19600000ull    // float[8*128] banked BN sum (zeroed) = 4096
#define ACC2_OFF     19604096ull    // float[8*128] banked BN sumsq (zeroed) = 4096
#define ZERO_OFF     19200000ull
#define ZERO_BYTES   408192ull      // cursor+dego+acc1+acc2 (contiguous)
#define OUTPRE_OFF   23000064ull    // bf16-packed [50000*64 dwords] = 12,800,000

typedef short bf16x8 __attribute__((ext_vector_type(8)));
typedef float f32x4  __attribute__((ext_vector_type(4)));

__device__ __forceinline__ float bf16lo(unsigned int v) { return __uint_as_float(v << 16); }
__device__ __forceinline__ float bf16hi(unsigned int v) { return __uint_as_float(v & 0xffff0000u); }
__device__ __forceinline__ unsigned int packbf16(float x, float y) {
  union { __hip_bfloat162 v; unsigned int u; } cvt;
  cvt.v.x = __float2bfloat16(x);
  cvt.v.y = __float2bfloat16(y);
  return cvt.u;
}

// dtype self-detect: 64-sample per-wave ballot on h's first dwords.
__device__ __forceinline__ int detect_bf16(const unsigned int* hu, int tid) {
  unsigned int u = hu[tid & 63];
  int ex = (u >> 7) & 0xFF;
  unsigned long long b = __ballot(ex >= 100 && ex <= 140);
  return __popcll(b) >= 32 ? 1 : 0;
}

// ---------------- fused: GEMM (Z = h@W, unscaled) || CSR build + dego -------
// Champion structure (R1/R5): GEMM blocks [0,782), build blocks [782,3126).
// deg scales commute with the GEMM; applied per-src at gather.
// Build is bound by memory-side atomic service (~1.2M RMWs ~= 60us floor,
// robust across layouts per R0/R1/R2); the GEMM rides free in that shadow.
__global__ __launch_bounds__(256) void k_fused(const int* __restrict__ src,
                                               const int* __restrict__ dst,
                                               int* __restrict__ cursor,
                                               int* __restrict__ dego,
                                               unsigned short* __restrict__ esrcPad,
                                               const void* __restrict__ hraw,
                                               const void* __restrict__ Wraw,
                                               __hip_bfloat16* __restrict__ Z) {
  __shared__ unsigned int lb[8192];      // swizzled W B-frags (32 KB) -> 5 blocks/CU
  int t = threadIdx.x;

  if (blockIdx.x >= GEMM_BLOCKS) {
    // ---- build path: 2 atomics + dependent 2B scatter per edge ----
    int e = (blockIdx.x - GEMM_BLOCKS) * 256 + t;
    if (e < N_EDGES) {
      int s = src[e];
      int d = dst[e];
      atomicAdd(&dego[s], 1);
      int slot = atomicAdd(&cursor[d], 1);
      if (slot < SLOTS) esrcPad[(size_t)d * SLOTS + slot] = (unsigned short)s;
    }
    return;
  }

  // ---- GEMM path ----
  const unsigned int* hu = (const unsigned int*)hraw;
  int isbf = detect_bf16(hu, t);
  int r0 = blockIdx.x * 64;

  // inline W swizzle: global W -> LDS B-frag layout (hidden under build shadow)
  for (int i = t; i < 8192; i += 256) {
    int tileIdx = i >> 8;
    int rem     = i & 255;
    int ln      = rem >> 2;
    int dw      = rem & 3;
    int kb      = tileIdx & 3;
    int ct      = tileIdx >> 2;
    int q       = ln >> 4;
    int n       = ln & 15;
    int k       = kb * 32 + q * 8 + dw * 2;
    int c       = ct * 16 + n;
    unsigned int val;
    if (isbf) {
      const unsigned int* Wd = (const unsigned int*)Wraw;
      unsigned int u0 = Wd[k * 64 + (c >> 1)];
      unsigned int u1 = Wd[(k + 1) * 64 + (c >> 1)];
      unsigned int h0 = (c & 1) ? (u0 >> 16) : (u0 & 0xffffu);
      unsigned int h1 = (c & 1) ? (u1 >> 16) : (u1 & 0xffffu);
      val = h0 | (h1 << 16);
    } else {
      const float* Wf = (const float*)Wraw;
      val = packbf16(Wf[k * 128 + c], Wf[(k + 1) * 128 + c]);
    }
    lb[i] = val;
  }

  int l = t & 63;
  int w = t >> 6;
  int m = l & 15;
  int q = l >> 4;

  int rA = r0 + w * 16 + m;
  bool okA = rA < N_NODES;

  // A fragments straight from global h, converted inline
  bf16x8 af[4];
  if (isbf) {
    const uint4* hd = (const uint4*)hraw;
#pragma unroll
    for (int kb = 0; kb < 4; ++kb) {
      union { uint4 u; bf16x8 v; } cv;
      cv.u = okA ? hd[(size_t)rA * 16 + kb * 4 + q] : make_uint4(0u, 0u, 0u, 0u);
      af[kb] = cv.v;
    }
  } else {
    const float4* hf = (const float4*)hraw;
#pragma unroll
    for (int kb = 0; kb < 4; ++kb) {
      union { uint4 u; bf16x8 v; } cv;
      if (okA) {
        float4 f0 = hf[(size_t)rA * 32 + kb * 8 + q * 2];
        float4 f1 = hf[(size_t)rA * 32 + kb * 8 + q * 2 + 1];
        cv.u.x = packbf16(f0.x, f0.y);
        cv.u.y = packbf16(f0.z, f0.w);
        cv.u.z = packbf16(f1.x, f1.y);
        cv.u.w = packbf16(f1.z, f1.w);
      } else {
        cv.u = make_uint4(0u, 0u, 0u, 0u);
      }
      af[kb] = cv.v;
    }
  }

  f32x4 acc[8];
#pragma unroll
  for (int ct = 0; ct < 8; ++ct) acc[ct] = (f32x4){0.f, 0.f, 0.f, 0.f};

  __syncthreads();

#pragma unroll
  for (int kb = 0; kb < 4; ++kb) {
#pragma unroll
    for (int ct = 0; ct < 8; ++ct) {
      bf16x8 bfv = *(const bf16x8*)&lb[(ct * 4 + kb) * 256 + l * 4];
      acc[ct] = __builtin_amdgcn_mfma_f32_16x16x32_bf16(af[kb], bfv, acc[ct], 0, 0, 0);
    }
  }

#pragma unroll
  for (int ct = 0; ct < 8; ++ct) {
    int col = ct * 16 + m;
#pragma unroll
    for (int reg = 0; reg < 4; ++reg) {
      int row = r0 + w * 16 + q * 4 + reg;
      if (row < N_NODES) Z[(size_t)row * 128 + col] = __float2bfloat16(acc[ct][reg]);
    }
  }
}

// ---------------- gather over Z (x rsqrt(deg_out[src])) + banked BN acc -----
// Gather identical to R5. BN partials are accumulated fire-and-forget into
// 8 banked global accumulators via atomicAdd (memory-side, XCD-coherent).
// NO fence, NO done-counter, NO finalize -> none of R7's 3125-fence cache
// destruction. The kernel boundary publishes the accumulators to k_post.
__global__ __launch_bounds__(256) void k_gatherZ(const unsigned int* __restrict__ Zd,
                                                 const int* __restrict__ cursor,
                                                 const int* __restrict__ dego,
                                                 const unsigned short* __restrict__ esrcPad,
                                                 unsigned int* __restrict__ outpre,
                                                 float* __restrict__ acc1,
                                                 float* __restrict__ acc2) {
  __shared__ float sred[8 * 128];   // [0,512): sum partials, [512,1024): sq partials
  int t = threadIdx.x;
  int w = t >> 6;
  int l = t & 63;
  float s1a = 0.f, s1b = 0.f, s2a = 0.f, s2b = 0.f;
#pragma unroll
  for (int i = 0; i < 4; ++i) {
    int n = blockIdx.x * 16 + w * 4 + i;       // covers 0..49999 exactly
    int di = cursor[n];
    int cnt = di < SLOTS ? di : SLOTS;
    const unsigned short* row = esrcPad + (size_t)n * SLOTS;
    float a0 = 0.f, a1 = 0.f;
    int j = 0;
    for (; j + 3 < cnt; j += 4) {
      ushort4 s4 = *(const ushort4*)&row[j];
      int i0 = s4.x, i1 = s4.y, i2 = s4.z, i3 = s4.w;
      unsigned int v0 = Zd[(size_t)i0 * 64 + l];
      unsigned int v1 = Zd[(size_t)i1 * 64 + l];
      unsigned int v2 = Zd[(size_t)i2 * 64 + l];
      unsigned int v3 = Zd[(size_t)i3 * 64 + l];
      float c0 = rsqrtf((float)max(dego[i0], 1));
      float c1 = rsqrtf((float)max(dego[i1], 1));
      float c2 = rsqrtf((float)max(dego[i2], 1));
      float c3 = rsqrtf((float)max(dego[i3], 1));
      a0 = fmaf(bf16lo(v0), c0, a0); a1 = fmaf(bf16hi(v0), c0, a1);
      a0 = fmaf(bf16lo(v1), c1, a0); a1 = fmaf(bf16hi(v1), c1, a1);
      a0 = fmaf(bf16lo(v2), c2, a0); a1 = fmaf(bf16hi(v2), c2, a1);
      a0 = fmaf(bf16lo(v3), c3, a0); a1 = fmaf(bf16hi(v3), c3, a1);
    }
    for (; j < cnt; ++j) {
      int is = row[j];
      unsigned int v = Zd[(size_t)is * 64 + l];
      float c = rsqrtf((float)max(dego[is], 1));
      a0 = fmaf(bf16lo(v), c, a0);
      a1 = fmaf(bf16hi(v), c, a1);
    }
    float scn = rsqrtf((float)(di < 1 ? 1 : di));
    a0 *= scn; a1 *= scn;
    outpre[(size_t)n * 64 + l] = packbf16(a0, a1);
    s1a += a0; s2a += a0 * a0;
    s1b += a1; s2b += a1 * a1;
  }
  sred[w * 128 + 2 * l]           = s1a;
  sred[w * 128 + 2 * l + 1]       = s1b;
  sred[512 + w * 128 + 2 * l]     = s2a;
  sred[512 + w * 128 + 2 * l + 1] = s2b;
  __syncthreads();
  int bank = (blockIdx.x & (ACC_BANKS - 1)) * 128;
  if (t < 128) {
    atomicAdd(&acc1[bank + t], sred[t] + sred[128 + t] + sred[256 + t] + sred[384 + t]);
    atomicAdd(&acc2[bank + t], sred[512 + t] + sred[640 + t] + sred[768 + t] + sred[896 + t]);
  }
}

// ---------------- BN finalize (redundant per block) + ReLU + L2 norm --------
// Each block redundantly reduces the 8 banks (8 KB of L2-broadcast reads),
// computes scale/shift into LDS, then applies BN+ReLU+rownorm to its 4 rows.
// Zero cross-block communication -> no spin, no fence, deterministic.
__global__ __launch_bounds__(256) void k_post(const unsigned int* __restrict__ outpre,
                                              const float* __restrict__ acc1,
                                              const float* __restrict__ acc2,
                                              const void* __restrict__ gamma,
                                              const void* __restrict__ beta,
                                              const unsigned int* __restrict__ hu,
                                              void* __restrict__ outraw) {
  __shared__ float sf[256];          // [0,128): scale, [128,256): shift
  int t = threadIdx.x;
  int isbf = detect_bf16(hu, t);
  if (t < 128) {
    float S1 = 0.f, S2 = 0.f;
#pragma unroll
    for (int k = 0; k < ACC_BANKS; ++k) {
      S1 += acc1[k * 128 + t];
      S2 += acc2[k * 128 + t];
    }
    const float invN = 1.0f / (float)N_NODES;
    float mu  = S1 * invN;
    float var = S2 * invN - mu * mu;
    float is  = rsqrtf(var + 1e-5f);
    float g, b;
    if (isbf) {
      g = __bfloat162float(((const __hip_bfloat16*)gamma)[t]);
      b = __bfloat162float(((const __hip_bfloat16*)beta)[t]);
    } else {
      g = ((const float*)gamma)[t];
      b = ((const float*)beta)[t];
    }
    sf[t]       = g * is;
    sf[128 + t] = b - mu * g * is;
  }
  __syncthreads();

  int r = blockIdx.x * 4 + (t >> 6);   // grid = N_NODES/4 exactly
  int l = t & 63;
  unsigned int xv = outpre[(size_t)r * 64 + l];
  float2 sc; sc.x = sf[2 * l];       sc.y = sf[2 * l + 1];
  float2 sh; sh.x = sf[128 + 2 * l]; sh.y = sf[128 + 2 * l + 1];
  float y0 = fmaxf(bf16lo(xv) * sc.x + sh.x, 0.f);
  float y1 = fmaxf(bf16hi(xv) * sc.y + sh.y, 0.f);
  float ss = y0 * y0 + y1 * y1;
#pragma unroll
  for (int o = 1; o < 64; o <<= 1) ss += __shfl_xor(ss, o, 64);
  float inv = 1.0f / fmaxf(sqrtf(ss), 1e-12f);
  y0 *= inv; y1 *= inv;
  if (isbf) {
    ((unsigned int*)outraw)[(size_t)r * 64 + l] = packbf16(y0, y1);
  } else {
    float2 o2; o2.x = y0; o2.y = y1;
    ((float2*)outraw)[(size_t)r * 64 + l] = o2;
  }
}

extern "C" void kernel_launch(void* const* d_in, const int* in_sizes, int n_in,
                              void* d_out, int out_size, void* d_ws, size_t ws_size,
                              hipStream_t stream) {
  const void* h     = d_in[0];
  const void* W     = d_in[1];
  const void* gamma = d_in[2];
  const void* beta  = d_in[3];
  const int*  src   = (const int*)d_in[4];
  const int*  dst   = (const int*)d_in[5];

  char* ws = (char*)d_ws;
  unsigned int* Zd        = (unsigned int*)(ws + Z_OFF);
  unsigned short* esrcPad = (unsigned short*)(ws + ESRCP_OFF);
  int*   cursor  = (int*)(ws + CURS_OFF);
  int*   dego    = (int*)(ws + DEGO_OFF);
  float* acc1    = (float*)(ws + ACC1_OFF);
  float* acc2    = (float*)(ws + ACC2_OFF);
  unsigned int* outpre = (unsigned int*)(ws + OUTPRE_OFF);   // bf16-packed

  (void)hipMemsetAsync(ws + ZERO_OFF, 0, ZERO_BYTES, stream);

  hipLaunchKernelGGL(k_fused, dim3(TOTAL_BLOCKS), dim3(256), 0, stream,
                     src, dst, cursor, dego, esrcPad, h, W, (__hip_bfloat16*)Zd);
  hipLaunchKernelGGL(k_gatherZ, dim3(GATHER_BLOCKS), dim3(256), 0, stream,
                     Zd, cursor, dego, esrcPad, outpre, acc1, acc2);
  hipLaunchKernelGGL(k_post, dim3(N_NODES / 4), dim3(256), 0, stream,
                     outpre, acc1, acc2, gamma, beta,
                     (const unsigned int*)h, (unsigned int*)d_out);
}